// Round 8
// baseline (4220.744 us; speedup 1.0000x reference)
//
#include <hip/hip_runtime.h>
#include <hip/hip_bf16.h>

#define BB 256      // batch
#define CC 2048     // code_num
#define HD 1024     // hidden
#define TT 64       // max_len
#define H3 3072
#define NBLK 256
#define NGRP 8      // groups of batch rows
#define GBLK 32     // blocks per group
#define GROWS 32    // batch rows per group

typedef __attribute__((ext_vector_type(8)))  short bf16x8;
typedef __attribute__((ext_vector_type(4)))  float f32x4;
typedef __attribute__((ext_vector_type(16))) float f32x16;
typedef __attribute__((ext_vector_type(4)))  int   i32x4;

__device__ __forceinline__ float sigmoidf_(float x){ return 1.0f/(1.0f+__expf(-x)); }
__device__ __forceinline__ float tanhf_(float x){ float e=__expf(2.0f*x); return 1.0f - 2.0f/(e+1.0f); }
__device__ __forceinline__ unsigned short bfbits(float x){
  __hip_bfloat16 b = __float2bfloat16(x);
  return *reinterpret_cast<unsigned short*>(&b);
}
__device__ __forceinline__ void st_sys_bf16(__hip_bfloat16* p, float v){
  __hip_atomic_store((unsigned short*)p, bfbits(v), __ATOMIC_RELAXED, __HIP_MEMORY_SCOPE_SYSTEM);
}
__device__ __forceinline__ float ld_sys_bf16v(const __hip_bfloat16* p){
  unsigned short b = __hip_atomic_load((const unsigned short*)p, __ATOMIC_RELAXED, __HIP_MEMORY_SCOPE_SYSTEM);
  union { unsigned short u; __hip_bfloat16 h; } x; x.u = b;
  return __bfloat162float(x.h);
}
// 16B system-coherent load (L2-bypass). Must waitv0() before consuming.
__device__ __forceinline__ i32x4 ld_sys16(const void* p){
  i32x4 r;
  asm volatile("global_load_dwordx4 %0, %1, off sc0 sc1"
               : "=v"(r) : "v"(p) : "memory");
  return r;
}
__device__ __forceinline__ void waitv0(){
  asm volatile("s_waitcnt vmcnt(0)" ::: "memory");
  __builtin_amdgcn_sched_barrier(0);
}

__global__ void cvt_f32_bf16(const float* __restrict__ in, __hip_bfloat16* __restrict__ out, int n){
  int i = (blockIdx.x*blockDim.x + threadIdx.x)*4;
  int stride = gridDim.x*blockDim.x*4;
  for (; i < n; i += stride){
    float4 v = *reinterpret_cast<const float4*>(in + i);
    ushort4 s;
    s.x = bfbits(v.x); s.y = bfbits(v.y); s.z = bfbits(v.z); s.w = bfbits(v.w);
    *reinterpret_cast<ushort4*>(out + i) = s;
  }
}

#define MFMA32(a,b,c) __builtin_amdgcn_mfma_f32_32x32x16_bf16((a),(b),(c),0,0,0)

// Persistent GRU, 256 blocks x 1024 threads (16 waves), 1 block/CU (LDS>80KB).
// blockIdx = g*32 + bsub. Group g owns batch rows [g*32,+32); bsub owns
// 32 H-cols (cell/gh) and 64 C-cols (codes).
// Per step t:
//   X(t): stage h_t (or noise at t=0) -> codes_t = sig(h_t Wout) [samples t],
//         gh_t = h_t Whh (kept in LDS, zeros at t=0)
//   Y(t): stage codes_t -> gi = codes_t Wih; combine with gh_t, h_t ->
//         h_{t+1} [hiddens t]
// Inter-block sync: monotonic per-block flag generations with REAL
// release/acquire fences (__threadfence_system) -- the round-7 version used
// relaxed stores + syncthreads-drain only, which raced on graph replays
// (0xAA-poisoned workspace exposed it).
__global__ __launch_bounds__(1024, 4) void gru_persistent(
    const __hip_bfloat16* __restrict__ wih,     // [3H][C]
    const __hip_bfloat16* __restrict__ whh,     // [3H][H]
    const __hip_bfloat16* __restrict__ wout,    // [C][H]
    const __hip_bfloat16* __restrict__ noise16, // [B][H]
    const float* __restrict__ bih,
    const float* __restrict__ bhh,
    const float* __restrict__ bout,
    float* __restrict__ samples,                // [B][T][C]
    float* __restrict__ hiddens,                // [B][T][H]
    __hip_bfloat16* cb0, __hip_bfloat16* cb1,   // [B][C] codes ping-pong
    __hip_bfloat16* hb0, __hip_bfloat16* hb1,   // [B][H] h ping-pong
    unsigned* flagC, unsigned* flagH)
{
  // 96KB act/dump arena (panels 0..63 = 64KB used; padding forces 1 block/CU)
  __shared__ __align__(16) char actbuf[98304];
  __shared__ float ghbuf[3*4*256];             // 12KB: [gate][q][lane*4]

  const int tid  = threadIdx.x;
  const int lane = tid & 63;
  const int wid  = tid >> 6;      // 0..15
  const int g    = blockIdx.x >> 5;
  const int bsub = blockIdx.x & 31;
  const int lrow = lane & 31;     // fragment row/col index
  const int lkg  = lane >> 5;     // fragment k-group (0/1)

  auto signal = [&](unsigned* flags, unsigned gen){
    __syncthreads();              // all waves' stores issued + vmcnt-drained
    if (tid == 0){
      __threadfence_system();     // RELEASE: commit prior writes to coherent pt
      __hip_atomic_store(&flags[g*GBLK + bsub], gen, __ATOMIC_RELAXED, __HIP_MEMORY_SCOPE_SYSTEM);
    }
  };
  auto waitf = [&](unsigned* flags, unsigned gen){
    if (tid < GBLK){
      while (__hip_atomic_load(&flags[g*GBLK + tid], __ATOMIC_RELAXED, __HIP_MEMORY_SCOPE_SYSTEM) < gen)
        __builtin_amdgcn_s_sleep(2);
      __threadfence_system();     // ACQUIRE: no stale lines after the poll
    }
    __syncthreads();
  };

  // Stage 64 fragment panels (64KB) of activation rows [g*32,+32) into actbuf.
  // Panel p holds A-frag for k-range [colBase+p*16, +16): lane l gets
  // row (l&31), k-elems colBase + p*16 + (l>>5)*8 .. +8.
  auto stage = [&](const __hip_bfloat16* src, int rowStride, int colBase){
    i32x4 r0, r1, r2, r3;
    {
      int s = tid;        int p = s>>6, l = s&63;
      r0 = ld_sys16(src + (size_t)(g*GROWS + (l&31))*rowStride + colBase + p*16 + (l>>5)*8);
    }{
      int s = tid+1024;   int p = s>>6, l = s&63;
      r1 = ld_sys16(src + (size_t)(g*GROWS + (l&31))*rowStride + colBase + p*16 + (l>>5)*8);
    }{
      int s = tid+2048;   int p = s>>6, l = s&63;
      r2 = ld_sys16(src + (size_t)(g*GROWS + (l&31))*rowStride + colBase + p*16 + (l>>5)*8);
    }{
      int s = tid+3072;   int p = s>>6, l = s&63;
      r3 = ld_sys16(src + (size_t)(g*GROWS + (l&31))*rowStride + colBase + p*16 + (l>>5)*8);
    }
    waitv0();
    { int s = tid;      *(i32x4*)(actbuf + (s>>6)*1024 + (s&63)*16) = r0; }
    { int s = tid+1024; *(i32x4*)(actbuf + (s>>6)*1024 + (s&63)*16) = r1; }
    { int s = tid+2048; *(i32x4*)(actbuf + (s>>6)*1024 + (s&63)*16) = r2; }
    { int s = tid+3072; *(i32x4*)(actbuf + (s>>6)*1024 + (s&63)*16) = r3; }
  };

  auto dumpAcc = [&](int slot, const f32x16& acc){
    char* base = actbuf + slot*4096 + lane*16;
#pragma unroll
    for (int q = 0; q < 4; q++){
      f32x4 v = { acc[q*4+0], acc[q*4+1], acc[q*4+2], acc[q*4+3] };
      *(f32x4*)(base + q*1024) = v;
    }
  };

  const f32x16 zacc = {0};

  // ---------------- phase X ----------------
  auto phaseX = [&](const __hip_bfloat16* hsrc, __hip_bfloat16* codesDst, int t){
    stage(hsrc, HD, 0);
    __syncthreads();

    if (wid < 15){
      const int tile = wid / 3;        // 0,1: Wout cols; 2,3,4: Whh gates
      const int ks   = wid % 3;
      const int fbeg = (ks == 0) ? 0 : (22 + 21*(ks-1));
      const int fend = (ks == 2) ? 64 : (22 + 21*ks);
      const __hip_bfloat16* wl;
      if (tile < 2) wl = wout + (size_t)(bsub*64 + tile*32 + lrow)*HD + lkg*8;
      else          wl = whh  + (size_t)((tile-2)*HD + bsub*32 + lrow)*HD + lkg*8;
      f32x16 acc = zacc;
#pragma unroll 8
      for (int f = fbeg; f < fend; f++){
        bf16x8 a = *(const bf16x8*)(actbuf + f*1024 + lane*16);
        bf16x8 b = *(const bf16x8*)(wl + f*16);
        acc = MFMA32(a, b, acc);
      }
      __syncthreads();
      dumpAcc(wid, acc);            // slot == wid == tile*3+ks
    } else {
      __syncthreads();
    }
    __syncthreads();

    if (wid < 8){
      // codes reduction: tile = wid>>2 (0/1), q = wid&3
      const int tile = wid >> 2, q = wid & 3;
      const int col  = bsub*64 + tile*32 + lrow;
      f32x4 s0 = *(const f32x4*)(actbuf + (tile*3+0)*4096 + q*1024 + lane*16);
      f32x4 s1 = *(const f32x4*)(actbuf + (tile*3+1)*4096 + q*1024 + lane*16);
      f32x4 s2 = *(const f32x4*)(actbuf + (tile*3+2)*4096 + q*1024 + lane*16);
      const float bo = bout[col];
#pragma unroll
      for (int j = 0; j < 4; j++){
        const int row  = j + 8*q + 4*lkg;
        const int brow = g*GROWS + row;
        float sv = sigmoidf_(s0[j] + s1[j] + s2[j] + bo);
        __builtin_nontemporal_store(sv, &samples[(size_t)brow*TT*CC + (size_t)t*CC + col]);
        st_sys_bf16(codesDst + (size_t)brow*CC + col, sv);
      }
    } else {
      // gh reduction -> ghbuf (zeros at t==0): tasks (gate,q), 12 over 8 waves
      for (int task = wid - 8; task < 12; task += 8){
        const int gt = task >> 2, q = task & 3;
        f32x4 r;
        if (t == 0){
          r = (f32x4){0.f,0.f,0.f,0.f};
        } else {
          f32x4 s0 = *(const f32x4*)(actbuf + ((2+gt)*3+0)*4096 + q*1024 + lane*16);
          f32x4 s1 = *(const f32x4*)(actbuf + ((2+gt)*3+1)*4096 + q*1024 + lane*16);
          f32x4 s2 = *(const f32x4*)(actbuf + ((2+gt)*3+2)*4096 + q*1024 + lane*16);
          r = (f32x4){ s0[0]+s1[0]+s2[0], s0[1]+s1[1]+s2[1],
                       s0[2]+s1[2]+s2[2], s0[3]+s1[3]+s2[3] };
        }
        *(f32x4*)&ghbuf[(gt*4+q)*256 + lane*4] = r;
      }
    }
  };

  // ---------------- phase Y ----------------
  auto phaseY = [&](const __hip_bfloat16* codesSrc, const __hip_bfloat16* hsrc,
                    __hip_bfloat16* hDst, int t){
    f32x16 acc = zacc;
    float hp[4]; float bI[3], bH[3];
    const int jcol = bsub*32 + lrow;

    // half 0
    stage(codesSrc, CC, 0);
    __syncthreads();
    if (wid < 12){
      const int gt = wid >> 2, ks = wid & 3;
      const __hip_bfloat16* wl = wih + (size_t)(gt*HD + bsub*32 + lrow)*CC + lkg*8;
#pragma unroll
      for (int i = 0; i < 16; i++){
        const int f = ks*16 + i;
        bf16x8 a = *(const bf16x8*)(actbuf + f*1024 + lane*16);
        bf16x8 b = *(const bf16x8*)(wl + f*16);
        acc = MFMA32(a, b, acc);
      }
    } else {
      // epilogue-wave prefetch (concurrent with compute)
      const int q = wid - 12;
#pragma unroll
      for (int j = 0; j < 4; j++){
        const int row = j + 8*q + 4*lkg;
        hp[j] = (t == 0) ? 0.0f
              : ld_sys_bf16v(hsrc + (size_t)(g*GROWS + row)*HD + jcol);
      }
#pragma unroll
      for (int gt = 0; gt < 3; gt++){
        bI[gt] = bih[gt*HD + jcol];
        bH[gt] = bhh[gt*HD + jcol];
      }
    }
    __syncthreads();

    // half 1
    stage(codesSrc, CC, 1024);
    __syncthreads();
    if (wid < 12){
      const int gt = wid >> 2, ks = wid & 3;
      const __hip_bfloat16* wl = wih + (size_t)(gt*HD + bsub*32 + lrow)*CC + lkg*8;
#pragma unroll
      for (int i = 0; i < 16; i++){
        const int f = ks*16 + i;
        bf16x8 a = *(const bf16x8*)(actbuf + f*1024 + lane*16);
        bf16x8 b = *(const bf16x8*)(wl + 1024 + f*16);
        acc = MFMA32(a, b, acc);
      }
      __syncthreads();
      dumpAcc(wid, acc);            // slot == wid == gt*4+ks
    } else {
      __syncthreads();
    }
    __syncthreads();

    if (wid >= 12){
      const int q = wid - 12;
      f32x4 gi[3], gh[3];
#pragma unroll
      for (int gt = 0; gt < 3; gt++){
        f32x4 s0 = *(const f32x4*)(actbuf + (gt*4+0)*4096 + q*1024 + lane*16);
        f32x4 s1 = *(const f32x4*)(actbuf + (gt*4+1)*4096 + q*1024 + lane*16);
        f32x4 s2 = *(const f32x4*)(actbuf + (gt*4+2)*4096 + q*1024 + lane*16);
        f32x4 s3 = *(const f32x4*)(actbuf + (gt*4+3)*4096 + q*1024 + lane*16);
        gi[gt] = (f32x4){ s0[0]+s1[0]+s2[0]+s3[0], s0[1]+s1[1]+s2[1]+s3[1],
                          s0[2]+s1[2]+s2[2]+s3[2], s0[3]+s1[3]+s2[3]+s3[3] };
        gh[gt] = *(const f32x4*)&ghbuf[(gt*4+q)*256 + lane*4];
      }
#pragma unroll
      for (int j = 0; j < 4; j++){
        const int row  = j + 8*q + 4*lkg;
        const int brow = g*GROWS + row;
        float r = sigmoidf_(gi[0][j] + gh[0][j] + bI[0] + bH[0]);
        float z = sigmoidf_(gi[1][j] + gh[1][j] + bI[1] + bH[1]);
        float n = tanhf_(gi[2][j] + bI[2] + r*(gh[2][j] + bH[2]));
        float hv = (1.0f - z)*n + z*hp[j];
        __builtin_nontemporal_store(hv, &hiddens[(size_t)brow*TT*HD + (size_t)t*HD + jcol]);
        st_sys_bf16(hDst + (size_t)brow*HD + jcol, hv);
      }
    }
  };

  // ---------------- sequence ----------------
#pragma unroll 1
  for (int t = 0; t < TT; t++){
    const __hip_bfloat16* hcur = (t & 1) ? hb1 : hb0;   // h_t (t>=1)
    __hip_bfloat16* codesCur   = (t & 1) ? cb1 : cb0;   // codes_t dst
    __hip_bfloat16* hnext      = (t & 1) ? hb0 : hb1;   // h_{t+1} dst

    if (t > 0) waitf(flagH, (unsigned)t);
    phaseX((t == 0) ? noise16 : hcur, codesCur, t);
    signal(flagC, (unsigned)(t+1));

    waitf(flagC, (unsigned)(t+1));
    phaseY(codesCur, hcur, hnext, t);
    signal(flagH, (unsigned)(t+1));
  }
}

extern "C" void kernel_launch(void* const* d_in, const int* in_sizes, int n_in,
                              void* d_out, int out_size, void* d_ws, size_t ws_size,
                              hipStream_t stream) {
  const float* noise = (const float*)d_in[0];
  const float* W_ih  = (const float*)d_in[1];
  const float* b_ih  = (const float*)d_in[2];
  const float* W_hh  = (const float*)d_in[3];
  const float* b_hh  = (const float*)d_in[4];
  const float* W_out = (const float*)d_in[5];
  const float* b_out = (const float*)d_in[6];

  float* samples = (float*)d_out;                       // [B][T][C]
  float* hiddens = samples + (size_t)BB*TT*CC;          // [B][T][H]

  char* w = (char*)d_ws;
  unsigned* flagC = (unsigned*)w;              w += 1024;   // 256 u32
  unsigned* flagH = (unsigned*)w;              w += 1024;
  __hip_bfloat16* wih16 = (__hip_bfloat16*)w;  w += (size_t)H3*CC*2;
  __hip_bfloat16* whh16 = (__hip_bfloat16*)w;  w += (size_t)H3*HD*2;
  __hip_bfloat16* wout16= (__hip_bfloat16*)w;  w += (size_t)CC*HD*2;
  __hip_bfloat16* noise16=(__hip_bfloat16*)w;  w += (size_t)BB*HD*2;
  __hip_bfloat16* cb0   = (__hip_bfloat16*)w;  w += (size_t)BB*CC*2;
  __hip_bfloat16* cb1   = (__hip_bfloat16*)w;  w += (size_t)BB*CC*2;
  __hip_bfloat16* hb0   = (__hip_bfloat16*)w;  w += (size_t)BB*HD*2;
  __hip_bfloat16* hb1   = (__hip_bfloat16*)w;  w += (size_t)BB*HD*2;

  hipMemsetAsync(flagC, 0, 2048, stream);
  cvt_f32_bf16<<<2048, 256, 0, stream>>>(W_ih,  wih16,  H3*CC);
  cvt_f32_bf16<<<2048, 256, 0, stream>>>(W_hh,  whh16,  H3*HD);
  cvt_f32_bf16<<<1024, 256, 0, stream>>>(W_out, wout16, CC*HD);
  cvt_f32_bf16<<<256,  256, 0, stream>>>(noise, noise16, BB*HD);

  gru_persistent<<<NBLK, 1024, 0, stream>>>(
      wih16, whh16, wout16, noise16, b_ih, b_hh, b_out,
      samples, hiddens, cb0, cb1, hb0, hb1, flagC, flagH);
}

// Round 9
// 3516.194 us; speedup vs baseline: 1.2004x; 1.2004x over previous
//
#include <hip/hip_runtime.h>
#include <hip/hip_bf16.h>

#define BB 256      // batch
#define CC 2048     // code_num
#define HD 1024     // hidden
#define TT 64       // max_len
#define H3 3072
#define NBLK 256
#define NGRP 8      // groups of batch rows
#define GBLK 32     // blocks per group
#define GROWS 32    // batch rows per group

typedef __attribute__((ext_vector_type(8)))  short bf16x8;
typedef __attribute__((ext_vector_type(4)))  float f32x4;
typedef __attribute__((ext_vector_type(16))) float f32x16;
typedef __attribute__((ext_vector_type(4)))  int   i32x4;

__device__ __forceinline__ float sigmoidf_(float x){ return 1.0f/(1.0f+__expf(-x)); }
__device__ __forceinline__ float tanhf_(float x){ float e=__expf(2.0f*x); return 1.0f - 2.0f/(e+1.0f); }
__device__ __forceinline__ unsigned short bfbits(float x){
  __hip_bfloat16 b = __float2bfloat16(x);
  return *reinterpret_cast<unsigned short*>(&b);
}
__device__ __forceinline__ void st_sys_bf16(__hip_bfloat16* p, float v){
  __hip_atomic_store((unsigned short*)p, bfbits(v), __ATOMIC_RELAXED, __HIP_MEMORY_SCOPE_SYSTEM);
}
__device__ __forceinline__ float ld_sys_bf16v(const __hip_bfloat16* p){
  unsigned short b = __hip_atomic_load((const unsigned short*)p, __ATOMIC_RELAXED, __HIP_MEMORY_SCOPE_SYSTEM);
  union { unsigned short u; __hip_bfloat16 h; } x; x.u = b;
  return __bfloat162float(x.h);
}
// 16B system-coherent load (L2-bypass). Must waitv0() before consuming.
__device__ __forceinline__ i32x4 ld_sys16(const void* p){
  i32x4 r;
  asm volatile("global_load_dwordx4 %0, %1, off sc0 sc1"
               : "=v"(r) : "v"(p) : "memory");
  return r;
}
__device__ __forceinline__ void waitv0(){
  asm volatile("s_waitcnt vmcnt(0)" ::: "memory");
  __builtin_amdgcn_sched_barrier(0);
}
// RELEASE: flush dirty L2 lines (activation sc-stores) to the L3 coherence
// point WITHOUT invalidating clean lines (weights stay L2-resident).
__device__ __forceinline__ void release_wb(){
  asm volatile("s_waitcnt vmcnt(0)\n\t"
               "buffer_wbl2 sc1\n\t"
               "s_waitcnt vmcnt(0)" ::: "memory");
}

__global__ void cvt_f32_bf16(const float* __restrict__ in, __hip_bfloat16* __restrict__ out, int n){
  int i = (blockIdx.x*blockDim.x + threadIdx.x)*4;
  int stride = gridDim.x*blockDim.x*4;
  for (; i < n; i += stride){
    float4 v = *reinterpret_cast<const float4*>(in + i);
    ushort4 s;
    s.x = bfbits(v.x); s.y = bfbits(v.y); s.z = bfbits(v.z); s.w = bfbits(v.w);
    *reinterpret_cast<ushort4*>(out + i) = s;
  }
}

#define MFMA32(a,b,c) __builtin_amdgcn_mfma_f32_32x32x16_bf16((a),(b),(c),0,0,0)

// Persistent GRU, 256 blocks x 1024 threads (16 waves), 1 block/CU (LDS>80KB).
// blockIdx = g*32 + bsub. Group g owns batch rows [g*32,+32); bsub owns
// 32 H-cols (cell/gh) and 64 C-cols (codes). Same-bsub blocks are congruent
// mod 8 -> same XCD under round-robin dispatch -> per-XCD weight working set
// = 4 bsub slices ~ 2.8MB < 4MB L2, and with NO invalidating fences anywhere
// the weights stay L2-resident across all 64 steps.
// Sync protocol: monotonic per-block flag generations. signal = syncthreads
// (drains all waves' stores) + tid0 {wbl2 writeback, flag store}. waitf =
// relaxed sc-scope poll + syncthreads (no acquire fence needed: all
// cross-block data moves via sc0sc1 ops that bypass L1/L2).
__global__ __launch_bounds__(1024, 4) void gru_persistent(
    const __hip_bfloat16* __restrict__ wih,     // [3H][C]
    const __hip_bfloat16* __restrict__ whh,     // [3H][H]
    const __hip_bfloat16* __restrict__ wout,    // [C][H]
    const __hip_bfloat16* __restrict__ noise16, // [B][H]
    const float* __restrict__ bih,
    const float* __restrict__ bhh,
    const float* __restrict__ bout,
    float* __restrict__ samples,                // [B][T][C]
    float* __restrict__ hiddens,                // [B][T][H]
    __hip_bfloat16* cb0, __hip_bfloat16* cb1,   // [B][C] codes ping-pong
    __hip_bfloat16* hb0, __hip_bfloat16* hb1,   // [B][H] h ping-pong
    unsigned* flagC, unsigned* flagH)
{
  // 96KB act/dump arena (panels 0..63 = 64KB used; padding forces 1 block/CU)
  __shared__ __align__(16) char actbuf[98304];
  __shared__ float ghbuf[3*4*256];             // 12KB: [gate][q][lane*4]

  const int tid  = threadIdx.x;
  const int lane = tid & 63;
  const int wid  = tid >> 6;      // 0..15
  const int g    = blockIdx.x >> 5;
  const int bsub = blockIdx.x & 31;
  const int lrow = lane & 31;     // fragment row/col index
  const int lkg  = lane >> 5;     // fragment k-group (0/1)

  auto signal = [&](unsigned* flags, unsigned gen){
    __syncthreads();              // all waves' stores issued + vmcnt-drained
    if (tid == 0){
      release_wb();               // writeback dirty lines; NO invalidate
      __hip_atomic_store(&flags[g*GBLK + bsub], gen, __ATOMIC_RELAXED, __HIP_MEMORY_SCOPE_SYSTEM);
    }
  };
  auto waitf = [&](unsigned* flags, unsigned gen){
    if (tid < GBLK){
      while (__hip_atomic_load(&flags[g*GBLK + tid], __ATOMIC_RELAXED, __HIP_MEMORY_SCOPE_SYSTEM) < gen)
        __builtin_amdgcn_s_sleep(2);
    }
    __syncthreads();              // no acquire fence: sc-reads bypass L1/L2
  };

  // Stage 64 fragment panels (64KB) of activation rows [g*32,+32) into actbuf.
  // Panel p holds A-frag for k-range [colBase+p*16, +16): lane l gets
  // row (l&31), k-elems colBase + p*16 + (l>>5)*8 .. +8.
  auto stage = [&](const __hip_bfloat16* src, int rowStride, int colBase){
    i32x4 r0, r1, r2, r3;
    {
      int s = tid;        int p = s>>6, l = s&63;
      r0 = ld_sys16(src + (size_t)(g*GROWS + (l&31))*rowStride + colBase + p*16 + (l>>5)*8);
    }{
      int s = tid+1024;   int p = s>>6, l = s&63;
      r1 = ld_sys16(src + (size_t)(g*GROWS + (l&31))*rowStride + colBase + p*16 + (l>>5)*8);
    }{
      int s = tid+2048;   int p = s>>6, l = s&63;
      r2 = ld_sys16(src + (size_t)(g*GROWS + (l&31))*rowStride + colBase + p*16 + (l>>5)*8);
    }{
      int s = tid+3072;   int p = s>>6, l = s&63;
      r3 = ld_sys16(src + (size_t)(g*GROWS + (l&31))*rowStride + colBase + p*16 + (l>>5)*8);
    }
    waitv0();
    { int s = tid;      *(i32x4*)(actbuf + (s>>6)*1024 + (s&63)*16) = r0; }
    { int s = tid+1024; *(i32x4*)(actbuf + (s>>6)*1024 + (s&63)*16) = r1; }
    { int s = tid+2048; *(i32x4*)(actbuf + (s>>6)*1024 + (s&63)*16) = r2; }
    { int s = tid+3072; *(i32x4*)(actbuf + (s>>6)*1024 + (s&63)*16) = r3; }
  };

  auto dumpAcc = [&](int slot, const f32x16& acc){
    char* base = actbuf + slot*4096 + lane*16;
#pragma unroll
    for (int q = 0; q < 4; q++){
      f32x4 v = { acc[q*4+0], acc[q*4+1], acc[q*4+2], acc[q*4+3] };
      *(f32x4*)(base + q*1024) = v;
    }
  };

  const f32x16 zacc = {0};

  // ---------------- phase X ----------------
  auto phaseX = [&](const __hip_bfloat16* hsrc, __hip_bfloat16* codesDst, int t){
    stage(hsrc, HD, 0);
    __syncthreads();

    if (wid < 15){
      const int tile = wid / 3;        // 0,1: Wout cols; 2,3,4: Whh gates
      const int ks   = wid % 3;
      const int fbeg = (ks == 0) ? 0 : (22 + 21*(ks-1));
      const int fend = (ks == 2) ? 64 : (22 + 21*ks);
      const __hip_bfloat16* wl;
      if (tile < 2) wl = wout + (size_t)(bsub*64 + tile*32 + lrow)*HD + lkg*8;
      else          wl = whh  + (size_t)((tile-2)*HD + bsub*32 + lrow)*HD + lkg*8;
      f32x16 acc = zacc;
#pragma unroll 8
      for (int f = fbeg; f < fend; f++){
        bf16x8 a = *(const bf16x8*)(actbuf + f*1024 + lane*16);
        bf16x8 b = *(const bf16x8*)(wl + f*16);
        acc = MFMA32(a, b, acc);
      }
      __syncthreads();
      dumpAcc(wid, acc);            // slot == wid == tile*3+ks
    } else {
      __syncthreads();
    }
    __syncthreads();

    if (wid < 8){
      // codes reduction: tile = wid>>2 (0/1), q = wid&3
      const int tile = wid >> 2, q = wid & 3;
      const int col  = bsub*64 + tile*32 + lrow;
      f32x4 s0 = *(const f32x4*)(actbuf + (tile*3+0)*4096 + q*1024 + lane*16);
      f32x4 s1 = *(const f32x4*)(actbuf + (tile*3+1)*4096 + q*1024 + lane*16);
      f32x4 s2 = *(const f32x4*)(actbuf + (tile*3+2)*4096 + q*1024 + lane*16);
      const float bo = bout[col];
#pragma unroll
      for (int j = 0; j < 4; j++){
        const int row  = j + 8*q + 4*lkg;
        const int brow = g*GROWS + row;
        float sv = sigmoidf_(s0[j] + s1[j] + s2[j] + bo);
        __builtin_nontemporal_store(sv, &samples[(size_t)brow*TT*CC + (size_t)t*CC + col]);
        st_sys_bf16(codesDst + (size_t)brow*CC + col, sv);
      }
    } else {
      // gh reduction -> ghbuf (zeros at t==0): tasks (gate,q), 12 over 8 waves
      for (int task = wid - 8; task < 12; task += 8){
        const int gt = task >> 2, q = task & 3;
        f32x4 r;
        if (t == 0){
          r = (f32x4){0.f,0.f,0.f,0.f};
        } else {
          f32x4 s0 = *(const f32x4*)(actbuf + ((2+gt)*3+0)*4096 + q*1024 + lane*16);
          f32x4 s1 = *(const f32x4*)(actbuf + ((2+gt)*3+1)*4096 + q*1024 + lane*16);
          f32x4 s2 = *(const f32x4*)(actbuf + ((2+gt)*3+2)*4096 + q*1024 + lane*16);
          r = (f32x4){ s0[0]+s1[0]+s2[0], s0[1]+s1[1]+s2[1],
                       s0[2]+s1[2]+s2[2], s0[3]+s1[3]+s2[3] };
        }
        *(f32x4*)&ghbuf[(gt*4+q)*256 + lane*4] = r;
      }
    }
  };

  // ---------------- phase Y ----------------
  auto phaseY = [&](const __hip_bfloat16* codesSrc, const __hip_bfloat16* hsrc,
                    __hip_bfloat16* hDst, int t){
    f32x16 acc = zacc;
    float hp[4]; float bI[3], bH[3];
    const int jcol = bsub*32 + lrow;

    // half 0
    stage(codesSrc, CC, 0);
    __syncthreads();
    if (wid < 12){
      const int gt = wid >> 2, ks = wid & 3;
      const __hip_bfloat16* wl = wih + (size_t)(gt*HD + bsub*32 + lrow)*CC + lkg*8;
#pragma unroll
      for (int i = 0; i < 16; i++){
        const int f = ks*16 + i;
        bf16x8 a = *(const bf16x8*)(actbuf + f*1024 + lane*16);
        bf16x8 b = *(const bf16x8*)(wl + f*16);
        acc = MFMA32(a, b, acc);
      }
    } else {
      // epilogue-wave prefetch (concurrent with compute)
      const int q = wid - 12;
#pragma unroll
      for (int j = 0; j < 4; j++){
        const int row = j + 8*q + 4*lkg;
        hp[j] = (t == 0) ? 0.0f
              : ld_sys_bf16v(hsrc + (size_t)(g*GROWS + row)*HD + jcol);
      }
#pragma unroll
      for (int gt = 0; gt < 3; gt++){
        bI[gt] = bih[gt*HD + jcol];
        bH[gt] = bhh[gt*HD + jcol];
      }
    }
    __syncthreads();

    // half 1
    stage(codesSrc, CC, 1024);
    __syncthreads();
    if (wid < 12){
      const int gt = wid >> 2, ks = wid & 3;
      const __hip_bfloat16* wl = wih + (size_t)(gt*HD + bsub*32 + lrow)*CC + lkg*8;
#pragma unroll
      for (int i = 0; i < 16; i++){
        const int f = ks*16 + i;
        bf16x8 a = *(const bf16x8*)(actbuf + f*1024 + lane*16);
        bf16x8 b = *(const bf16x8*)(wl + 1024 + f*16);
        acc = MFMA32(a, b, acc);
      }
      __syncthreads();
      dumpAcc(wid, acc);            // slot == wid == gt*4+ks
    } else {
      __syncthreads();
    }
    __syncthreads();

    if (wid >= 12){
      const int q = wid - 12;
      f32x4 gi[3], gh[3];
#pragma unroll
      for (int gt = 0; gt < 3; gt++){
        f32x4 s0 = *(const f32x4*)(actbuf + (gt*4+0)*4096 + q*1024 + lane*16);
        f32x4 s1 = *(const f32x4*)(actbuf + (gt*4+1)*4096 + q*1024 + lane*16);
        f32x4 s2 = *(const f32x4*)(actbuf + (gt*4+2)*4096 + q*1024 + lane*16);
        f32x4 s3 = *(const f32x4*)(actbuf + (gt*4+3)*4096 + q*1024 + lane*16);
        gi[gt] = (f32x4){ s0[0]+s1[0]+s2[0]+s3[0], s0[1]+s1[1]+s2[1]+s3[1],
                          s0[2]+s1[2]+s2[2]+s3[2], s0[3]+s1[3]+s2[3]+s3[3] };
        gh[gt] = *(const f32x4*)&ghbuf[(gt*4+q)*256 + lane*4];
      }
#pragma unroll
      for (int j = 0; j < 4; j++){
        const int row  = j + 8*q + 4*lkg;
        const int brow = g*GROWS + row;
        float r = sigmoidf_(gi[0][j] + gh[0][j] + bI[0] + bH[0]);
        float z = sigmoidf_(gi[1][j] + gh[1][j] + bI[1] + bH[1]);
        float n = tanhf_(gi[2][j] + bI[2] + r*(gh[2][j] + bH[2]));
        float hv = (1.0f - z)*n + z*hp[j];
        __builtin_nontemporal_store(hv, &hiddens[(size_t)brow*TT*HD + (size_t)t*HD + jcol]);
        st_sys_bf16(hDst + (size_t)brow*HD + jcol, hv);
      }
    }
  };

  // ---------------- sequence ----------------
#pragma unroll 1
  for (int t = 0; t < TT; t++){
    const __hip_bfloat16* hcur = (t & 1) ? hb1 : hb0;   // h_t (t>=1)
    __hip_bfloat16* codesCur   = (t & 1) ? cb1 : cb0;   // codes_t dst
    __hip_bfloat16* hnext      = (t & 1) ? hb0 : hb1;   // h_{t+1} dst

    if (t > 0) waitf(flagH, (unsigned)t);
    phaseX((t == 0) ? noise16 : hcur, codesCur, t);
    signal(flagC, (unsigned)(t+1));

    waitf(flagC, (unsigned)(t+1));
    phaseY(codesCur, hcur, hnext, t);
    signal(flagH, (unsigned)(t+1));
  }
}

extern "C" void kernel_launch(void* const* d_in, const int* in_sizes, int n_in,
                              void* d_out, int out_size, void* d_ws, size_t ws_size,
                              hipStream_t stream) {
  const float* noise = (const float*)d_in[0];
  const float* W_ih  = (const float*)d_in[1];
  const float* b_ih  = (const float*)d_in[2];
  const float* W_hh  = (const float*)d_in[3];
  const float* b_hh  = (const float*)d_in[4];
  const float* W_out = (const float*)d_in[5];
  const float* b_out = (const float*)d_in[6];

  float* samples = (float*)d_out;                       // [B][T][C]
  float* hiddens = samples + (size_t)BB*TT*CC;          // [B][T][H]

  char* w = (char*)d_ws;
  unsigned* flagC = (unsigned*)w;              w += 1024;   // 256 u32
  unsigned* flagH = (unsigned*)w;              w += 1024;
  __hip_bfloat16* wih16 = (__hip_bfloat16*)w;  w += (size_t)H3*CC*2;
  __hip_bfloat16* whh16 = (__hip_bfloat16*)w;  w += (size_t)H3*HD*2;
  __hip_bfloat16* wout16= (__hip_bfloat16*)w;  w += (size_t)CC*HD*2;
  __hip_bfloat16* noise16=(__hip_bfloat16*)w;  w += (size_t)BB*HD*2;
  __hip_bfloat16* cb0   = (__hip_bfloat16*)w;  w += (size_t)BB*CC*2;
  __hip_bfloat16* cb1   = (__hip_bfloat16*)w;  w += (size_t)BB*CC*2;
  __hip_bfloat16* hb0   = (__hip_bfloat16*)w;  w += (size_t)BB*HD*2;
  __hip_bfloat16* hb1   = (__hip_bfloat16*)w;  w += (size_t)BB*HD*2;

  hipMemsetAsync(flagC, 0, 2048, stream);
  cvt_f32_bf16<<<2048, 256, 0, stream>>>(W_ih,  wih16,  H3*CC);
  cvt_f32_bf16<<<2048, 256, 0, stream>>>(W_hh,  whh16,  H3*HD);
  cvt_f32_bf16<<<1024, 256, 0, stream>>>(W_out, wout16, CC*HD);
  cvt_f32_bf16<<<256,  256, 0, stream>>>(noise, noise16, BB*HD);

  gru_persistent<<<NBLK, 1024, 0, stream>>>(
      wih16, whh16, wout16, noise16, b_ih, b_hh, b_out,
      samples, hiddens, cb0, cb1, hb0, hb1, flagC, flagH);
}